// Round 7
// baseline (55.249 us; speedup 1.0000x reference)
//
#include <hip/hip_runtime.h>

#define FEAT    4096
#define NACT    512
#define THREADS 64
#define EPT     64              // one wave processes a full row
#define KRANK   (FEAT - NACT)   // 3584: ascending rank of smallest kept elem
#define FLO     0.8f
#define FHI     1.5f
#define RBINS   1024
#define MAXCAND 64

// Order-preserving float32 <-> uint32 key transform (fallback path only).
__device__ __forceinline__ unsigned f2key(float f) {
    unsigned b = __float_as_uint(f);
    return (b & 0x80000000u) ? ~b : (b | 0x80000000u);
}
__device__ __forceinline__ float key2f(unsigned k) {
    unsigned b = (k & 0x80000000u) ? (k & 0x7fffffffu) : ~k;
    return __uint_as_float(b);
}

// Swizzled histogram slot: lane L's 16 bins (16L..16L+15) live at L + 64*i
// -> scan reads are lane-consecutive b32 (conflict-free).
__device__ __forceinline__ unsigned binslot(unsigned b) {
    return (b >> 4) | ((b & 15u) << 6);
}

__global__ __launch_bounds__(THREADS, 4) void normactive_kernel(
        const float* __restrict__ in, float* __restrict__ out) {
    const int lane = threadIdx.x;        // single wave per block
    const float* rp = in  + (size_t)blockIdx.x * FEAT;
    float*       op = out + (size_t)blockIdx.x * FEAT;

    __shared__ __align__(16) unsigned buf[RBINS];     // 4 KB: range hist / fallback hist
    __shared__ unsigned long long cand[MAXCAND];
    __shared__ unsigned s_n;

    // ---- Load full row into registers: 16x float4 per lane, coalesced.
    float xv[EPT];
    #pragma unroll
    for (int c = 0; c < 16; ++c) {
        float4 t = reinterpret_cast<const float4*>(rp)[c * THREADS + lane];
        xv[4*c+0] = t.x; xv[4*c+1] = t.y; xv[4*c+2] = t.z; xv[4*c+3] = t.w;
    }

    // ---- Zero histogram + counter.
    uint4 z; z.x = z.y = z.z = z.w = 0u;
    #pragma unroll
    for (int i = 0; i < 4; ++i)
        reinterpret_cast<uint4*>(buf)[i * THREADS + lane] = z;
    if (lane == 0) s_n = 0;
    __syncthreads();   // single wave: compiles to ordering only

    // ---- Classify: count x > FHI; histogram x in (FLO, FHI] into 1024 bins.
    const float invw = (float)RBINS / (FHI - FLO);
    unsigned chi = 0;
    #pragma unroll
    for (int e = 0; e < EPT; ++e) {
        float x = xv[e];
        bool hi = (x > FHI);
        chi += hi ? 1u : 0u;
        if (x > FLO && !hi) {
            int bi = (int)((x - FLO) * invw);
            bi = bi < (RBINS - 1) ? bi : (RBINS - 1);
            atomicAdd(&buf[binslot((unsigned)bi)], 1u);
        }
    }
    #pragma unroll
    for (int off = 32; off >= 1; off >>= 1)
        chi += __shfl_xor(chi, (unsigned)off, 64);
    const int nHi = (int)chi;            // uniform across wave
    __syncthreads();                     // hist atomics visible

    // ---- Scan: lane L owns bins [16L, 16L+16) at slots L + 64*i.
    unsigned csum = 0;
    #pragma unroll
    for (int i = 0; i < 16; ++i)
        csum += buf[lane + (i << 6)];
    unsigned incl = csum;
    #pragma unroll
    for (int off = 1; off < 64; off <<= 1) {
        unsigned n = __shfl_up(incl, (unsigned)off, 64);
        if (lane >= off) incl += n;
    }
    const unsigned nIn  = __shfl(incl, 63);
    const unsigned excl = incl - csum;   // ascending prefix at bin 16*lane

    const int nLo  = FEAT - (int)nIn - nHi;
    const int need = NACT - nHi;         // kept elems still needed from binned region
    const int kkb  = KRANK - nLo;        // asc rank of boundary within binned region

    // mode: 0 = boundary in interior bin, 1 = threshold exactly FHI, 2 = generic
    int mode = (need > 0 && kkb >= 0 && kkb < (int)nIn) ? 0 : ((need == 0) ? 1 : 2);

    float vb = 0.0f;                     // boundary value
    int   ti = 0;                        // keep ==vb only when idx >= ti
    unsigned Bv = 0, kkv = 0, cntv = 0;

    if (mode == 0) {
        bool hit = false; unsigned myB = 0, myk = 0, myc = 0;
        unsigned run = excl;
        #pragma unroll
        for (int i = 0; i < 16; ++i) {
            unsigned ci = buf[lane + (i << 6)];
            if (!hit && (unsigned)kkb >= run && (unsigned)kkb < run + ci) {
                hit = true; myB = (unsigned)(16 * lane + i); myk = (unsigned)kkb - run; myc = ci;
            }
            run += ci;
        }
        unsigned long long m = __ballot(hit);
        int src = (int)(__ffsll((long long)m) - 1);
        Bv   = __shfl(myB, src);
        kkv  = __shfl(myk, src);
        cntv = __shfl(myc, src);
        if (cntv > MAXCAND) mode = 2;    // uniform decision
    }

    if (mode == 0) {
        // ---- Compact boundary-bin candidates as (bits << 32) | idx.
        // In-range values are positive -> uint-bit order == float order;
        // (value, idx) lexicographic == reference stable-sort tie rule.
        #pragma unroll
        for (int e = 0; e < EPT; ++e) {
            float x = xv[e];
            if (x > FLO && !(x > FHI)) {
                int bi = (int)((x - FLO) * invw);
                bi = bi < (RBINS - 1) ? bi : (RBINS - 1);
                if ((unsigned)bi == Bv) {
                    unsigned idx = (unsigned)((e >> 2) * 256 + lane * 4 + (e & 3));
                    unsigned pos = atomicAdd(&s_n, 1u);
                    cand[pos] = ((unsigned long long)__float_as_uint(x) << 32) | idx;
                }
            }
        }
        __syncthreads();
        unsigned long long my = (lane < (int)cntv) ? cand[lane] : ~0ull;
        unsigned r = 0;
        for (unsigned j = 0; j < cntv; ++j) {
            unsigned long long cj = __shfl(my, (int)j);
            r += (cj < my) ? 1u : 0u;
        }
        bool win = (lane < (int)cntv) && (r == kkv);   // exactly one lane
        unsigned long long m = __ballot(win);
        int src = (int)(__ffsll((long long)m) - 1);
        unsigned long long tb = __shfl(my, src);
        vb = __uint_as_float((unsigned)(tb >> 32));
        ti = (int)(tb & 0xffffffffu);
    } else if (mode == 1) {
        vb = FHI; ti = FEAT;             // keep = strictly > FHI (exactly 512)
    } else {
        // ---- Generic fallback (never taken for this input): single-wave
        // 4-pass 8-bit radix select + stable-tie index binary search.
        unsigned prefix = 0, kk = (unsigned)KRANK, nEq = 0;
        for (int pass = 0; pass < 4; ++pass) {
            const int shift = 24 - 8 * pass;
            reinterpret_cast<uint4*>(buf)[lane] = z;     // zero 256 bins
            __syncthreads();
            #pragma unroll
            for (int e = 0; e < EPT; ++e) {
                unsigned k = f2key(xv[e]);
                bool cp = (pass == 0) || ((k >> (shift + 8)) == prefix);
                if (cp) atomicAdd(&buf[(k >> shift) & 255u], 1u);
            }
            __syncthreads();
            uint4 c4 = reinterpret_cast<const uint4*>(buf)[lane];
            unsigned arr[4] = {c4.x, c4.y, c4.z, c4.w};
            unsigned s4 = arr[0] + arr[1] + arr[2] + arr[3];
            unsigned inc2 = s4;
            #pragma unroll
            for (int off = 1; off < 64; off <<= 1) {
                unsigned n = __shfl_up(inc2, (unsigned)off, 64);
                if (lane >= off) inc2 += n;
            }
            unsigned ex2 = inc2 - s4;
            bool hit = false; unsigned dg = 0, nk = 0, nc = 0, run = ex2;
            #pragma unroll
            for (int i = 0; i < 4; ++i) {
                unsigned ci = arr[i];
                if (!hit && kk >= run && kk < run + ci) {
                    hit = true; dg = (unsigned)(4 * lane + i); nk = kk - run; nc = ci;
                }
                run += ci;
            }
            unsigned long long m = __ballot(hit);
            int src = (int)(__ffsll((long long)m) - 1);
            prefix = (prefix << 8) | __shfl(dg, src);
            kk  = __shfl(nk, src);
            nEq = __shfl(nc, src);
            __syncthreads();
        }
        const unsigned K = prefix;
        const unsigned kEq = nEq - kk;
        int tIdx = 0;
        if (kk > 0) {
            int lo = 0, hi2 = FEAT;
            while (lo < hi2) {
                int mid = (lo + hi2 + 1) >> 1;
                unsigned c = 0;
                #pragma unroll
                for (int e = 0; e < EPT; ++e) {
                    int idx = (e >> 2) * 256 + lane * 4 + (e & 3);
                    if (f2key(xv[e]) == K && idx >= mid) ++c;
                }
                #pragma unroll
                for (int off = 32; off >= 1; off >>= 1)
                    c += __shfl_xor(c, (unsigned)off, 64);
                if (c >= kEq) lo = mid; else hi2 = mid - 1;
            }
            tIdx = lo;
        }
        vb = key2f(K);
        ti = tIdx;
    }

    // ---- Output: keep iff x > vb, or x == vb with idx >= ti. Exact x8 scale.
    #pragma unroll
    for (int c = 0; c < 16; ++c) {
        const int base = c * 256 + lane * 4;
        float a0 = xv[4*c+0], a1 = xv[4*c+1], a2 = xv[4*c+2], a3 = xv[4*c+3];
        float4 o;
        o.x = (a0 > vb || (a0 == vb && base + 0 >= ti)) ? a0 * 8.0f : 0.0f;
        o.y = (a1 > vb || (a1 == vb && base + 1 >= ti)) ? a1 * 8.0f : 0.0f;
        o.z = (a2 > vb || (a2 == vb && base + 2 >= ti)) ? a2 * 8.0f : 0.0f;
        o.w = (a3 > vb || (a3 == vb && base + 3 >= ti)) ? a3 * 8.0f : 0.0f;
        reinterpret_cast<float4*>(op)[c * THREADS + lane] = o;
    }
}

extern "C" void kernel_launch(void* const* d_in, const int* in_sizes, int n_in,
                              void* d_out, int out_size, void* d_ws, size_t ws_size,
                              hipStream_t stream) {
    const float* feat = (const float*)d_in[0];
    float* out = (float*)d_out;
    const int batch = in_sizes[0] / FEAT;  // 8192
    normactive_kernel<<<batch, THREADS, 0, stream>>>(feat, out);
}